// Round 1
// baseline (1566.448 us; speedup 1.0000x reference)
//
#include <hip/hip_runtime.h>
#include <cstdio>
#include <cstdint>

#define BB 16
#define HH 48
#define WW 48
#define DD 384
#define NTOK 2304            // HH*WW
#define EPS 1e-5f

typedef __attribute__((ext_vector_type(4))) float f32x4;
typedef __attribute__((ext_vector_type(8))) short bf16x8;
typedef __attribute__((ext_vector_type(4))) short bf16x4;

__device__ __forceinline__ unsigned short f2bf(float f) {
  uint32_t u = __float_as_uint(f);
  uint32_t r = (u + 0x7FFFu + ((u >> 16) & 1u)) >> 16;
  return (unsigned short)r;
}
__device__ __forceinline__ float bf2f(short s) {
  return __uint_as_float(((uint32_t)(unsigned short)s) << 16);
}

// ---------------- K1: x + posenc -> hi/lo bf16 ----------------
__global__ void k_prep(const float* __restrict__ x, const float* __restrict__ Wp,
                       const float* __restrict__ bp, short* __restrict__ xhi,
                       short* __restrict__ xlo) {
  size_t e = ((size_t)blockIdx.x * 256 + threadIdx.x) * 4;   // total = 13824*1024 exact
  int d = (int)(e % DD);
  int n = (int)((e / DD) % NTOK);
  float fh = (float)(n / WW), fw = (float)(n % WW);
  f32x4 v = *(const f32x4*)(x + e);
  bf16x4 hv, lv;
#pragma unroll
  for (int j = 0; j < 4; ++j) {
    float pe = fh * Wp[d + j] + fw * Wp[DD + d + j] + bp[d + j];
    float val = v[j] + pe;
    unsigned short hb = f2bf(val);
    hv[j] = (short)hb;
    lv[j] = (short)f2bf(val - bf2f((short)hb));
  }
  *(bf16x4*)(xhi + e) = hv;
  *(bf16x4*)(xlo + e) = lv;
}

// ---------------- K1T: per-batch transpose of hi -> xhiT[b][d][n] ----------------
__global__ void k_transpose(const short* __restrict__ xhi, short* __restrict__ xhiT) {
  __shared__ __attribute__((aligned(16))) short t[64 * 72];
  int tid = threadIdx.x;
  int d0 = blockIdx.x * 64, n0 = blockIdx.y * 64, b = blockIdx.z;
  const short* src = xhi + ((size_t)(b * NTOK + n0)) * DD + d0;
#pragma unroll
  for (int it = 0; it < 2; ++it) {
    int ci = tid + it * 256;
    int r = ci >> 3, c8 = ci & 7;
    *(bf16x8*)(&t[r * 72 + c8 * 8]) = *(const bf16x8*)(src + (size_t)r * DD + c8 * 8);
  }
  __syncthreads();
  short* dst = xhiT + ((size_t)b * DD + d0) * NTOK + n0;
#pragma unroll
  for (int it = 0; it < 2; ++it) {
    int ci = tid + it * 256;
    int dr = ci >> 3, m8 = ci & 7;
    bf16x8 v;
#pragma unroll
    for (int j = 0; j < 8; ++j) v[j] = t[(m8 * 8 + j) * 72 + dr];
    *(bf16x8*)(dst + (size_t)dr * NTOK + m8 * 8) = v;
  }
}

// ---------------- KW: W1^T, W2^T bf16 ----------------
__global__ void k_wprep(const float* __restrict__ W1, const float* __restrict__ W2,
                        short* __restrict__ w1t, short* __restrict__ w2t) {
  int idx = blockIdx.x * 256 + threadIdx.x;   // 147456 total
  int r = idx / DD, c = idx % DD;
  w1t[c * DD + r] = (short)f2bf(W1[idx]);
  w2t[c * DD + r] = (short)f2bf(W2[idx]);
}

// ---------------- K2: flash attention ----------------
#define KHI_STR 392
#define KLO_STR 136
#define VT_STR 72
#define P_STR 72
#define KHI_SZ (64 * KHI_STR)            // 25088 shorts
#define KLO_OFF KHI_SZ
#define SKV_SZ (KHI_SZ + 64 * KLO_STR)   // 33792 shorts

__global__ __launch_bounds__(256, 2)
void k_attn(const short* __restrict__ xhi, const short* __restrict__ xlo,
            const short* __restrict__ xhiT, short* __restrict__ aout) {
  __shared__ __attribute__((aligned(16))) short skv[SKV_SZ];
  __shared__ __attribute__((aligned(16))) short sp[4 * 16 * P_STR];
  const int tid = threadIdx.x;
  const int lane = tid & 63, wave = tid >> 6;
  const int ln15 = lane & 15, lg = lane >> 4;
  const int b = blockIdx.y;
  const int q0 = blockIdx.x * 64;

  // Q hi fragments in registers (B-operand: col=n=lane&15, k contiguous)
  bf16x8 qh[12];
  {
    const short* qp = xhi + ((size_t)(b * NTOK + q0 + wave * 16 + ln15)) * DD + lg * 8;
#pragma unroll
    for (int kf = 0; kf < 12; ++kf) qh[kf] = *(const bf16x8*)(qp + kf * 32);
  }
  const short* qlp = xlo + ((size_t)(b * NTOK + q0 + wave * 16 + ln15)) * DD + lg * 8;

  f32x4 o[24];
#pragma unroll
  for (int i = 0; i < 24; ++i) o[i] = f32x4{0.f, 0.f, 0.f, 0.f};
  float m1 = -INFINITY, l1 = 0.0f;

  const short* kbase = xhi + (size_t)b * NTOK * DD;
  const short* lbase = xlo + (size_t)b * NTOK * DD;
  const short* vbase = xhiT + (size_t)b * DD * NTOK;

#pragma unroll 1
  for (int mt = 0; mt < NTOK / 64; ++mt) {
    const int m0 = mt * 64;
    __syncthreads();                          // protect prev VT from PV reads
    {                                          // stage Khi full (64x384) + Klo chunk0
      const short* src = kbase + (size_t)m0 * DD;
#pragma unroll
      for (int it = 0; it < 12; ++it) {
        int ci = tid + it * 256;
        int row = ci / 48, c8 = ci % 48;
        *(bf16x8*)(&skv[row * KHI_STR + c8 * 8]) = *(const bf16x8*)(src + row * DD + c8 * 8);
      }
      const short* srcl = lbase + (size_t)m0 * DD;
#pragma unroll
      for (int it = 0; it < 4; ++it) {
        int ci = tid + it * 256;
        int row = ci >> 4, c8 = ci & 15;
        *(bf16x8*)(&skv[KLO_OFF + row * KLO_STR + c8 * 8]) =
            *(const bf16x8*)(srcl + row * DD + c8 * 8);
      }
    }
    f32x4 s[4];
#pragma unroll
    for (int i = 0; i < 4; ++i) s[i] = f32x4{0.f, 0.f, 0.f, 0.f};

#pragma unroll
    for (int c = 0; c < 3; ++c) {
      __syncthreads();                        // staged chunk ready
#pragma unroll
      for (int kfl = 0; kfl < 4; ++kfl) {
        const int kf = c * 4 + kfl;
        bf16x8 ql = *(const bf16x8*)(qlp + kf * 32);
#pragma unroll
        for (int cb = 0; cb < 4; ++cb) {
          const int arow = cb * 16 + ln15;
          bf16x8 ah  = *(const bf16x8*)(&skv[arow * KHI_STR + kf * 32 + lg * 8]);
          bf16x8 al2 = *(const bf16x8*)(&skv[KLO_OFF + arow * KLO_STR + kfl * 32 + lg * 8]);
          s[cb] = __builtin_amdgcn_mfma_f32_16x16x32_bf16(ah, qh[kf], s[cb], 0, 0, 0);
          s[cb] = __builtin_amdgcn_mfma_f32_16x16x32_bf16(ah, ql, s[cb], 0, 0, 0);
          s[cb] = __builtin_amdgcn_mfma_f32_16x16x32_bf16(al2, qh[kf], s[cb], 0, 0, 0);
        }
      }
      if (c < 2) {
        __syncthreads();                      // Klo chunk consumed
        const short* srcl = lbase + (size_t)m0 * DD + (c + 1) * 128;
#pragma unroll
        for (int it = 0; it < 4; ++it) {
          int ci = tid + it * 256;
          int row = ci >> 4, c8 = ci & 15;
          *(bf16x8*)(&skv[KLO_OFF + row * KLO_STR + c8 * 8]) =
              *(const bf16x8*)(srcl + row * DD + c8 * 8);
        }
      }
    }
    __syncthreads();                          // K consumed; safe to overwrite with VT
    {                                          // stage V^T (from pre-transposed xhiT)
#pragma unroll
      for (int it = 0; it < 12; ++it) {
        int ci = tid + it * 256;
        int d = ci >> 3, mc = ci & 7;
        *(bf16x8*)(&skv[d * VT_STR + mc * 8]) =
            *(const bf16x8*)(vbase + (size_t)d * NTOK + m0 + mc * 8);
      }
    }
    // ---- online softmax over columns of S^T (each lane owns column n = ln15) ----
    float tmax = -INFINITY;
#pragma unroll
    for (int cb = 0; cb < 4; ++cb)
#pragma unroll
      for (int r = 0; r < 4; ++r) tmax = fmaxf(tmax, s[cb][r]);
    tmax = fmaxf(tmax, __shfl_xor(tmax, 16));
    tmax = fmaxf(tmax, __shfl_xor(tmax, 32));
    const float mn = fmaxf(m1, tmax);
    const float al = __expf(m1 - mn);
    float rs = 0.0f;
#pragma unroll
    for (int cb = 0; cb < 4; ++cb) {
#pragma unroll
      for (int r = 0; r < 4; ++r) {
        float p = __expf(s[cb][r] - mn);
        s[cb][r] = p;
        rs += p;
      }
    }
    rs += __shfl_xor(rs, 16);
    rs += __shfl_xor(rs, 32);
    l1 = l1 * al + rs;
    m1 = mn;
    // write P^T (bf16) into per-wave [n][m] buffer
    short* pw = &sp[wave * 16 * P_STR + ln15 * P_STR];
#pragma unroll
    for (int cb = 0; cb < 4; ++cb) {
      bf16x4 pk;
#pragma unroll
      for (int r = 0; r < 4; ++r) pk[r] = (short)f2bf(s[cb][r]);
      *(bf16x4*)(&pw[cb * 16 + lg * 4]) = pk;
    }
    // rescale O (O rows are n = lg*4+r, stats live at lane n)
    float alr[4];
#pragma unroll
    for (int r = 0; r < 4; ++r) alr[r] = __shfl(al, lg * 4 + r);
#pragma unroll
    for (int ob = 0; ob < 24; ++ob)
#pragma unroll
      for (int r = 0; r < 4; ++r) o[ob][r] *= alr[r];
    __syncthreads();                          // VT + P ready
    // ---- PV: O[n][d] += P[n][m] * V[m][d] ----
    const short* prd = &sp[wave * 16 * P_STR + ln15 * P_STR + lg * 8];
    bf16x8 pa0 = *(const bf16x8*)(prd);
    bf16x8 pa1 = *(const bf16x8*)(prd + 32);
#pragma unroll
    for (int db = 0; db < 24; ++db) {
      const int vrow = db * 16 + ln15;
      bf16x8 v0 = *(const bf16x8*)(&skv[vrow * VT_STR + lg * 8]);
      bf16x8 v1 = *(const bf16x8*)(&skv[vrow * VT_STR + 32 + lg * 8]);
      o[db] = __builtin_amdgcn_mfma_f32_16x16x32_bf16(pa0, v0, o[db], 0, 0, 0);
      o[db] = __builtin_amdgcn_mfma_f32_16x16x32_bf16(pa1, v1, o[db], 0, 0, 0);
    }
  }
  // epilogue: O /= l, store bf16
  float lr[4];
#pragma unroll
  for (int r = 0; r < 4; ++r) lr[r] = __shfl(l1, lg * 4 + r);
  short* ob_ = aout + ((size_t)(b * NTOK + q0 + wave * 16)) * DD;
#pragma unroll
  for (int db = 0; db < 24; ++db) {
#pragma unroll
    for (int r = 0; r < 4; ++r) {
      float v = o[db][r] / lr[r];
      ob_[(size_t)(lg * 4 + r) * DD + db * 16 + ln15] = (short)f2bf(v);
    }
  }
}

// ---------------- K3: MLP + residual + LN stats ----------------
__global__ __launch_bounds__(256, 2)
void k_mlp(const short* __restrict__ aout, const short* __restrict__ w1t,
           const short* __restrict__ w2t, const float* __restrict__ b1,
           const float* __restrict__ b2, const short* __restrict__ xhi,
           const short* __restrict__ xlo, float* __restrict__ out,
           float* __restrict__ stats) {
  __shared__ __attribute__((aligned(16))) short hid[4 * 16 * 392];
  __shared__ float redS[4], redQ[4];
  const int tid = threadIdx.x, lane = tid & 63, wave = tid >> 6;
  const int ln15 = lane & 15, lg = lane >> 4;
  const int row0 = blockIdx.x * 64;
  const int bb = row0 / NTOK;

  bf16x8 a[12];
  {
    const short* ap = aout + (size_t)(row0 + wave * 16 + ln15) * DD + lg * 8;
#pragma unroll
    for (int kf = 0; kf < 12; ++kf) a[kf] = *(const bf16x8*)(ap + kf * 32);
  }
  short* hw = &hid[wave * 16 * 392];
#pragma unroll 1
  for (int cb = 0; cb < 24; ++cb) {
    f32x4 acc = f32x4{0.f, 0.f, 0.f, 0.f};
#pragma unroll
    for (int kf = 0; kf < 12; ++kf) {
      bf16x8 wf = *(const bf16x8*)(w1t + (size_t)(cb * 16 + ln15) * DD + kf * 32 + lg * 8);
      acc = __builtin_amdgcn_mfma_f32_16x16x32_bf16(a[kf], wf, acc, 0, 0, 0);
    }
    float bias = b1[cb * 16 + ln15];
#pragma unroll
    for (int r = 0; r < 4; ++r) {
      float v = fmaxf(acc[r] + bias, 0.0f);
      hw[(lg * 4 + r) * 392 + cb * 16 + ln15] = (short)f2bf(v);
    }
  }
  __syncthreads();   // (cheap; also orders per-wave LDS writes before cross-lane reads)
  bf16x8 h[12];
#pragma unroll
  for (int kf = 0; kf < 12; ++kf)
    h[kf] = *(const bf16x8*)(&hw[ln15 * 392 + kf * 32 + lg * 8]);
  float ts = 0.f, tq = 0.f;
#pragma unroll 1
  for (int cb = 0; cb < 24; ++cb) {
    f32x4 acc = f32x4{0.f, 0.f, 0.f, 0.f};
#pragma unroll
    for (int kf = 0; kf < 12; ++kf) {
      bf16x8 wf = *(const bf16x8*)(w2t + (size_t)(cb * 16 + ln15) * DD + kf * 32 + lg * 8);
      acc = __builtin_amdgcn_mfma_f32_16x16x32_bf16(h[kf], wf, acc, 0, 0, 0);
    }
    int col = cb * 16 + ln15;
    float bias = b2[col];
#pragma unroll
    for (int r = 0; r < 4; ++r) {
      size_t row = (size_t)row0 + wave * 16 + lg * 4 + r;
      size_t idx = row * DD + col;
      float xv = bf2f(xhi[idx]) + bf2f(xlo[idx]);
      float y = acc[r] + bias + xv;
      out[idx] = y;
      ts += y;
      tq += y * y;
    }
  }
#pragma unroll
  for (int off = 32; off; off >>= 1) {
    ts += __shfl_xor(ts, off);
    tq += __shfl_xor(tq, off);
  }
  if (lane == 0) { redS[wave] = ts; redQ[wave] = tq; }
  __syncthreads();
  if (tid == 0) {
    atomicAdd(&stats[bb], redS[0] + redS[1] + redS[2] + redS[3]);
    atomicAdd(&stats[16 + bb], redQ[0] + redQ[1] + redQ[2] + redQ[3]);
  }
}

// ---------------- K4: LayerNorm ----------------
__global__ void k_ln(float* __restrict__ out, const float* __restrict__ stats) {
  size_t i4 = ((size_t)blockIdx.x * 256 + threadIdx.x) * 4;
  int b = (int)(i4 / ((size_t)NTOK * DD));
  const float cnt = (float)(NTOK * DD);
  float mean = stats[b] / cnt;
  float var = stats[16 + b] / cnt - mean * mean;
  float inv = rsqrtf(var + EPS);
  f32x4 v = *(f32x4*)(out + i4);
#pragma unroll
  for (int j = 0; j < 4; ++j) v[j] = (v[j] - mean) * inv;
  *(f32x4*)(out + i4) = v;
}

// ---------------- launcher ----------------
extern "C" void kernel_launch(void* const* d_in, const int* in_sizes, int n_in,
                              void* d_out, int out_size, void* d_ws, size_t ws_size,
                              hipStream_t stream) {
  const float* x  = (const float*)d_in[0];
  const float* Wp = (const float*)d_in[1];
  const float* bp = (const float*)d_in[2];
  const float* W1 = (const float*)d_in[3];
  const float* b1 = (const float*)d_in[4];
  const float* W2 = (const float*)d_in[5];
  const float* b2 = (const float*)d_in[6];
  float* out = (float*)d_out;

  const size_t SZ = (size_t)BB * NTOK * DD * sizeof(short);   // 28,311,552
  char* ws = (char*)d_ws;
  short* xhi  = (short*)ws;
  short* xlo  = (short*)(ws + SZ);
  short* xhiT = (short*)(ws + 2 * SZ);
  short* aout = (short*)(ws + 3 * SZ);
  short* w1t  = (short*)(ws + 4 * SZ);
  short* w2t  = (short*)(ws + 4 * SZ + 294912);
  float* stats = (float*)(ws + 4 * SZ + 2 * 294912);
  const size_t need = 4 * SZ + 2 * 294912 + 128;
  if (ws_size < need) {
    fprintf(stderr, "kernel_launch: ws_size %zu < needed %zu\n", ws_size, need);
  }

  k_prep<<<13824, 256, 0, stream>>>(x, Wp, bp, xhi, xlo);
  k_transpose<<<dim3(6, 36, 16), 256, 0, stream>>>(xhi, xhiT);
  k_wprep<<<576, 256, 0, stream>>>(W1, W2, w1t, w2t);
  k_attn<<<dim3(36, 16), 256, 0, stream>>>(xhi, xlo, xhiT, aout);
  hipMemsetAsync(stats, 0, 32 * sizeof(float), stream);
  k_mlp<<<576, 256, 0, stream>>>(aout, w1t, w2t, b1, b2, xhi, xlo, out, stats);
  k_ln<<<13824, 256, 0, stream>>>(out, stats);
}

// Round 2
// 975.807 us; speedup vs baseline: 1.6053x; 1.6053x over previous
//
#include <hip/hip_runtime.h>
#include <cstdio>
#include <cstdint>

#define BB 16
#define HH 48
#define WW 48
#define DD 384
#define NTOK 2304            // HH*WW
#define EPS 1e-5f
#define SZB 28311552u        // BB*NTOK*DD*2 bytes (one bf16 tensor); xlo = xhi + SZB

typedef __attribute__((ext_vector_type(4))) float f32x4;
typedef __attribute__((ext_vector_type(8))) short bf16x8;
typedef __attribute__((ext_vector_type(4))) short bf16x4;

__device__ __forceinline__ unsigned short f2bf(float f) {
  uint32_t u = __float_as_uint(f);
  uint32_t r = (u + 0x7FFFu + ((u >> 16) & 1u)) >> 16;
  return (unsigned short)r;
}
__device__ __forceinline__ float bf2f(short s) {
  return __uint_as_float(((uint32_t)(unsigned short)s) << 16);
}

typedef __attribute__((address_space(3))) uint32_t lds_u32;
typedef __attribute__((address_space(1))) const uint32_t glob_u32;
__device__ __forceinline__ void gload_lds16(const void* g, void* l) {
  __builtin_amdgcn_global_load_lds((glob_u32*)g, (lds_u32*)l, 16, 0, 0);
}

// ---------------- K1: x + posenc -> hi/lo bf16 ----------------
__global__ void k_prep(const float* __restrict__ x, const float* __restrict__ Wp,
                       const float* __restrict__ bp, short* __restrict__ xhi,
                       short* __restrict__ xlo) {
  size_t e = ((size_t)blockIdx.x * 256 + threadIdx.x) * 4;
  int d = (int)(e % DD);
  int n = (int)((e / DD) % NTOK);
  float fh = (float)(n / WW), fw = (float)(n % WW);
  f32x4 v = *(const f32x4*)(x + e);
  bf16x4 hv, lv;
#pragma unroll
  for (int j = 0; j < 4; ++j) {
    float pe = fh * Wp[d + j] + fw * Wp[DD + d + j] + bp[d + j];
    float val = v[j] + pe;
    unsigned short hb = f2bf(val);
    hv[j] = (short)hb;
    lv[j] = (short)f2bf(val - bf2f((short)hb));
  }
  *(bf16x4*)(xhi + e) = hv;
  *(bf16x4*)(xlo + e) = lv;
}

// ---------------- K1T: per-batch transpose of hi -> xhiT[b][d][n] ----------------
__global__ void k_transpose(const short* __restrict__ xhi, short* __restrict__ xhiT) {
  __shared__ __attribute__((aligned(16))) short t[64 * 72];
  int tid = threadIdx.x;
  int d0 = blockIdx.x * 64, n0 = blockIdx.y * 64, b = blockIdx.z;
  const short* src = xhi + ((size_t)(b * NTOK + n0)) * DD + d0;
#pragma unroll
  for (int it = 0; it < 2; ++it) {
    int ci = tid + it * 256;
    int r = ci >> 3, c8 = ci & 7;
    *(bf16x8*)(&t[r * 72 + c8 * 8]) = *(const bf16x8*)(src + (size_t)r * DD + c8 * 8);
  }
  __syncthreads();
  short* dst = xhiT + ((size_t)b * DD + d0) * NTOK + n0;
#pragma unroll
  for (int it = 0; it < 2; ++it) {
    int ci = tid + it * 256;
    int dr = ci >> 3, m8 = ci & 7;
    bf16x8 v;
#pragma unroll
    for (int j = 0; j < 8; ++j) v[j] = t[(m8 * 8 + j) * 72 + dr];
    *(bf16x8*)(dst + (size_t)dr * NTOK + m8 * 8) = v;
  }
}

// ---------------- KW: W1^T, W2^T bf16 ----------------
__global__ void k_wprep(const float* __restrict__ W1, const float* __restrict__ W2,
                        short* __restrict__ w1t, short* __restrict__ w2t) {
  int idx = blockIdx.x * 256 + threadIdx.x;
  int r = idx / DD, c = idx % DD;
  w1t[c * DD + r] = (short)f2bf(W1[idx]);
  w2t[c * DD + r] = (short)f2bf(W2[idx]);
}

// ---------------- K2: flash attention (KVB=32, global_load_lds, 2 barriers/iter) ----
#define KVB 32
#define NIT 72               // NTOK / KVB

__global__ __launch_bounds__(256, 2)
void k_attn(const short* __restrict__ xhi, const short* __restrict__ xlo,
            const short* __restrict__ xhiT, short* __restrict__ aout) {
  // K tile: 32 rows x [hi 768B | lo 768B] = 1536B/row, XOR-swizzled (bits 4-6 by row&7)
  __shared__ __attribute__((aligned(16))) char sk[KVB * 1536];     // 49152 B
  __shared__ __attribute__((aligned(16))) char sv[DD * 64];        // 24576 B (VT [384][32] bf16)
  __shared__ __attribute__((aligned(16))) char sp[4 * 1024];       // P [16 q][32 m] bf16 per wave
  const int tid = threadIdx.x;
  const int lane = tid & 63, wave = tid >> 6;
  const int ln15 = lane & 15, lg = lane >> 4;
  const int b = blockIdx.y, q0 = blockIdx.x * 64;
  const int swz = (ln15 & 7) << 4;

  // --- precompute staging source offsets (dest is linear; source pre-swizzled) ---
  uint32_t kvo[12];
#pragma unroll
  for (int j = 0; j < 12; ++j) {
    int d = (wave * 12 + j) * 1024 + lane * 16;
    int m = d / 1536, cc = d - m * 1536;
    int c = cc ^ ((m & 7) << 4);
    kvo[j] = (uint32_t)(m * 768) + (c < 768 ? (uint32_t)c : (SZB + (uint32_t)(c - 768)));
  }
  uint32_t vvo[6];
#pragma unroll
  for (int j = 0; j < 6; ++j) {
    int dv = (wave * 6 + j) * 1024 + lane * 16;
    int dr = dv >> 6;
    vvo[j] = (uint32_t)(dr * (NTOK * 2) + (dv & 63));
  }
  const char* kb = (const char*)xhi + (size_t)b * NTOK * 768;       // batch K base (hi; lo via +SZB)
  const char* vb = (const char*)xhiT + (size_t)b * DD * NTOK * 2;   // batch VT base
  char* kdst = sk + wave * 12288;
  char* vdst = sv + wave * 6144;

  // --- Q hi fragments resident; Q lo streamed from global (L1-hot) ---
  bf16x8 qh[12];
  {
    const short* qp = xhi + ((size_t)b * NTOK + q0 + wave * 16 + ln15) * DD + lg * 8;
#pragma unroll
    for (int kf = 0; kf < 12; ++kf) qh[kf] = *(const bf16x8*)(qp + kf * 32);
  }
  const short* qlp = xlo + ((size_t)b * NTOK + q0 + wave * 16 + ln15) * DD + lg * 8;

  f32x4 o[24];
#pragma unroll
  for (int i = 0; i < 24; ++i) o[i] = f32x4{0.f, 0.f, 0.f, 0.f};
  float m1 = -INFINITY, l1 = 0.0f;

  // prologue: stage K(0)
  {
    const char* k0 = kb;
#pragma unroll
    for (int j = 0; j < 12; ++j) gload_lds16(k0 + kvo[j], kdst + j * 1024);
  }
  const char* knext = kb + KVB * 768;   // source for K(mt+1)
  const char* vcur = vb;                // source for VT(mt)
  __syncthreads();                      // K(0) ready

#pragma unroll 1
  for (int mt = 0; mt < NIT; ++mt) {
    // issue VT(mt) (async; hidden under QK)
#pragma unroll
    for (int j = 0; j < 6; ++j) gload_lds16(vcur + vvo[j], vdst + j * 1024);
    vcur += KVB * 2;

    // ---- QK^T (split-precision, 3 MFMAs per (kf,cb)) ----
    f32x4 s[2];
    s[0] = f32x4{0.f, 0.f, 0.f, 0.f};
    s[1] = f32x4{0.f, 0.f, 0.f, 0.f};
    const char* krow0 = sk + (size_t)ln15 * 1536;
    __builtin_amdgcn_s_setprio(1);
#pragma unroll
    for (int kf = 0; kf < 12; ++kf) {
      bf16x8 ql = *(const bf16x8*)(qlp + kf * 32);
      const int ca = (kf * 64 + lg * 16) ^ swz;
#pragma unroll
      for (int cb = 0; cb < 2; ++cb) {
        const char* ra = krow0 + cb * (16 * 1536) + ca;
        bf16x8 ah = *(const bf16x8*)(ra);
        bf16x8 al = *(const bf16x8*)(ra + 768);
        s[cb] = __builtin_amdgcn_mfma_f32_16x16x32_bf16(ah, qh[kf], s[cb], 0, 0, 0);
        s[cb] = __builtin_amdgcn_mfma_f32_16x16x32_bf16(ah, ql, s[cb], 0, 0, 0);
        s[cb] = __builtin_amdgcn_mfma_f32_16x16x32_bf16(al, qh[kf], s[cb], 0, 0, 0);
      }
    }
    __builtin_amdgcn_s_setprio(0);

    // ---- online softmax (lane owns q = ln15; m = cb*16 + lg*4 + r) ----
    float tmax = -INFINITY;
#pragma unroll
    for (int cb = 0; cb < 2; ++cb)
#pragma unroll
      for (int r = 0; r < 4; ++r) tmax = fmaxf(tmax, s[cb][r]);
    tmax = fmaxf(tmax, __shfl_xor(tmax, 16));
    tmax = fmaxf(tmax, __shfl_xor(tmax, 32));
    float mn, al_;
    if (__any(tmax - m1 > 8.f)) {          // defer-max: rescale only when max grows
      mn = fmaxf(m1, tmax);
      al_ = __expf(m1 - mn);
      float alr[4];
#pragma unroll
      for (int r = 0; r < 4; ++r) alr[r] = __shfl(al_, lg * 4 + r);
#pragma unroll
      for (int ob = 0; ob < 24; ++ob)
#pragma unroll
        for (int r = 0; r < 4; ++r) o[ob][r] *= alr[r];
    } else {
      mn = m1;
      al_ = 1.0f;
    }
    float rs = 0.0f;
#pragma unroll
    for (int cb = 0; cb < 2; ++cb)
#pragma unroll
      for (int r = 0; r < 4; ++r) {
        float p = __expf(s[cb][r] - mn);
        s[cb][r] = p;
        rs += p;
      }
    rs += __shfl_xor(rs, 16);
    rs += __shfl_xor(rs, 32);
    l1 = l1 * al_ + rs;
    m1 = mn;

    // P write: [q=ln15][m] bf16, per-wave buffer
    short* pw = (short*)(sp + wave * 1024) + ln15 * 32;
#pragma unroll
    for (int cb = 0; cb < 2; ++cb) {
      bf16x4 pk;
#pragma unroll
      for (int r = 0; r < 4; ++r) pk[r] = (short)f2bf(s[cb][r]);
      *(bf16x4*)(pw + cb * 16 + lg * 4) = pk;
    }

    __syncthreads();   // VT(mt) ready; all waves done reading K(mt)

    // issue K(mt+1) (async; hidden under PV)
    if (mt + 1 < NIT) {
#pragma unroll
      for (int j = 0; j < 12; ++j) gload_lds16(knext + kvo[j], kdst + j * 1024);
      knext += KVB * 768;
    }

    // ---- PV: O[q][d] += P[q][m] * VT[d][m], one MFMA per 16-d block ----
    bf16x8 pa = *(const bf16x8*)((short*)(sp + wave * 1024) + ln15 * 32 + lg * 8);
    __builtin_amdgcn_s_setprio(1);
#pragma unroll
    for (int db = 0; db < 24; ++db) {
      bf16x8 vfr = *(const bf16x8*)(sv + (db * 16 + ln15) * 64 + lg * 16);
      o[db] = __builtin_amdgcn_mfma_f32_16x16x32_bf16(pa, vfr, o[db], 0, 0, 0);
    }
    __builtin_amdgcn_s_setprio(0);

    __syncthreads();   // K(mt+1) ready; VT free for next overwrite
  }

  // epilogue: O /= l, store bf16
  float lr[4];
#pragma unroll
  for (int r = 0; r < 4; ++r) lr[r] = __shfl(l1, lg * 4 + r);
  short* ob_ = aout + ((size_t)b * NTOK + q0 + wave * 16) * DD;
#pragma unroll
  for (int db = 0; db < 24; ++db) {
#pragma unroll
    for (int r = 0; r < 4; ++r) {
      float v = o[db][r] / lr[r];
      ob_[(size_t)(lg * 4 + r) * DD + db * 16 + ln15] = (short)f2bf(v);
    }
  }
}

// ---------------- K3: MLP + residual + LN stats ----------------
__global__ __launch_bounds__(256, 2)
void k_mlp(const short* __restrict__ aout, const short* __restrict__ w1t,
           const short* __restrict__ w2t, const float* __restrict__ b1,
           const float* __restrict__ b2, const short* __restrict__ xhi,
           const short* __restrict__ xlo, float* __restrict__ out,
           float* __restrict__ stats) {
  __shared__ __attribute__((aligned(16))) short hid[4 * 16 * 392];
  __shared__ float redS[4], redQ[4];
  const int tid = threadIdx.x, lane = tid & 63, wave = tid >> 6;
  const int ln15 = lane & 15, lg = lane >> 4;
  const int row0 = blockIdx.x * 64;
  const int bb = row0 / NTOK;

  bf16x8 a[12];
  {
    const short* ap = aout + (size_t)(row0 + wave * 16 + ln15) * DD + lg * 8;
#pragma unroll
    for (int kf = 0; kf < 12; ++kf) a[kf] = *(const bf16x8*)(ap + kf * 32);
  }
  short* hw = &hid[wave * 16 * 392];
#pragma unroll 1
  for (int cb = 0; cb < 24; ++cb) {
    f32x4 acc = f32x4{0.f, 0.f, 0.f, 0.f};
#pragma unroll
    for (int kf = 0; kf < 12; ++kf) {
      bf16x8 wf = *(const bf16x8*)(w1t + (size_t)(cb * 16 + ln15) * DD + kf * 32 + lg * 8);
      acc = __builtin_amdgcn_mfma_f32_16x16x32_bf16(a[kf], wf, acc, 0, 0, 0);
    }
    float bias = b1[cb * 16 + ln15];
#pragma unroll
    for (int r = 0; r < 4; ++r) {
      float v = fmaxf(acc[r] + bias, 0.0f);
      hw[(lg * 4 + r) * 392 + cb * 16 + ln15] = (short)f2bf(v);
    }
  }
  __syncthreads();
  bf16x8 h[12];
#pragma unroll
  for (int kf = 0; kf < 12; ++kf)
    h[kf] = *(const bf16x8*)(&hw[ln15 * 392 + kf * 32 + lg * 8]);
  float ts = 0.f, tq = 0.f;
#pragma unroll 1
  for (int cb = 0; cb < 24; ++cb) {
    f32x4 acc = f32x4{0.f, 0.f, 0.f, 0.f};
#pragma unroll
    for (int kf = 0; kf < 12; ++kf) {
      bf16x8 wf = *(const bf16x8*)(w2t + (size_t)(cb * 16 + ln15) * DD + kf * 32 + lg * 8);
      acc = __builtin_amdgcn_mfma_f32_16x16x32_bf16(h[kf], wf, acc, 0, 0, 0);
    }
    int col = cb * 16 + ln15;
    float bias = b2[col];
#pragma unroll
    for (int r = 0; r < 4; ++r) {
      size_t row = (size_t)row0 + wave * 16 + lg * 4 + r;
      size_t idx = row * DD + col;
      float xv = bf2f(xhi[idx]) + bf2f(xlo[idx]);
      float y = acc[r] + bias + xv;
      out[idx] = y;
      ts += y;
      tq += y * y;
    }
  }
#pragma unroll
  for (int off = 32; off; off >>= 1) {
    ts += __shfl_xor(ts, off);
    tq += __shfl_xor(tq, off);
  }
  if (lane == 0) { redS[wave] = ts; redQ[wave] = tq; }
  __syncthreads();
  if (tid == 0) {
    atomicAdd(&stats[bb], redS[0] + redS[1] + redS[2] + redS[3]);
    atomicAdd(&stats[16 + bb], redQ[0] + redQ[1] + redQ[2] + redQ[3]);
  }
}

// ---------------- K4: LayerNorm ----------------
__global__ void k_ln(float* __restrict__ out, const float* __restrict__ stats) {
  size_t i4 = ((size_t)blockIdx.x * 256 + threadIdx.x) * 4;
  int b = (int)(i4 / ((size_t)NTOK * DD));
  const float cnt = (float)(NTOK * DD);
  float mean = stats[b] / cnt;
  float var = stats[16 + b] / cnt - mean * mean;
  float inv = rsqrtf(var + EPS);
  f32x4 v = *(f32x4*)(out + i4);
#pragma unroll
  for (int j = 0; j < 4; ++j) v[j] = (v[j] - mean) * inv;
  *(f32x4*)(out + i4) = v;
}

// ---------------- launcher ----------------
extern "C" void kernel_launch(void* const* d_in, const int* in_sizes, int n_in,
                              void* d_out, int out_size, void* d_ws, size_t ws_size,
                              hipStream_t stream) {
  const float* x  = (const float*)d_in[0];
  const float* Wp = (const float*)d_in[1];
  const float* bp = (const float*)d_in[2];
  const float* W1 = (const float*)d_in[3];
  const float* b1 = (const float*)d_in[4];
  const float* W2 = (const float*)d_in[5];
  const float* b2 = (const float*)d_in[6];
  float* out = (float*)d_out;

  const size_t SZ = (size_t)SZB;   // 28,311,552 bytes
  char* ws = (char*)d_ws;
  short* xhi  = (short*)ws;
  short* xlo  = (short*)(ws + SZ);      // MUST stay at xhi+SZB (staging offsets rely on it)
  short* xhiT = (short*)(ws + 2 * SZ);
  short* aout = (short*)(ws + 3 * SZ);
  short* w1t  = (short*)(ws + 4 * SZ);
  short* w2t  = (short*)(ws + 4 * SZ + 294912);
  float* stats = (float*)(ws + 4 * SZ + 2 * 294912);
  const size_t need = 4 * SZ + 2 * 294912 + 128;
  if (ws_size < need) {
    fprintf(stderr, "kernel_launch: ws_size %zu < needed %zu\n", ws_size, need);
  }

  k_prep<<<13824, 256, 0, stream>>>(x, Wp, bp, xhi, xlo);
  k_transpose<<<dim3(6, 36, 16), 256, 0, stream>>>(xhi, xhiT);
  k_wprep<<<576, 256, 0, stream>>>(W1, W2, w1t, w2t);
  k_attn<<<dim3(36, 16), 256, 0, stream>>>(xhi, xlo, xhiT, aout);
  hipMemsetAsync(stats, 0, 32 * sizeof(float), stream);
  k_mlp<<<576, 256, 0, stream>>>(aout, w1t, w2t, b1, b2, xhi, xlo, out, stats);
  k_ln<<<13824, 256, 0, stream>>>(out, stats);
}